// Round 12
// baseline (2907.777 us; speedup 1.0000x reference)
//
#include <hip/hip_runtime.h>
#include <hip/hip_fp16.h>

// Problem constants
#define TSTEPS 1024
#define HDIM   1024
#define INDIM  512
#define NGATE  4096     // 4*HDIM
#define NWG_L1  64
#define NWG_L23 128
#define NWG_TOT 192     // proven coop envelope
#define POISON_U 0x7C7C7C7Cu   // f16-pair poison; as f32 = 5.2e36 (unreachable)
#define SPIN_MAX (1 << 20)     // deadlock valve: fail loud, never hang

// ---------------------------------------------------------------------------
// R22 post-mortem: scan stuck ~2800 across variants; GEMM conflicts NOT on
// the critical path (R20 13.4M vs R22 6.7M, same dur). Remaining serialized
// latency identified: the h2[t-1]/h3[t-2] loads ISSUE at phase 2 -- by then
// the data is visible (stores were ~0.6-1.0us earlier), so the poll catches
// first-try, but its ~0.3us LLC latency is fully exposed every step
// (~300us total).
// R23 (ONE change): speculative EARLY ISSUE of the h2/h3 loads right after
// barrier A1, before the phase-1 dots -- the LLC RT overlaps the dot block;
// phase 2 validates the stashed value with the proven predicated spin.
// PINU anchor after the dots pins consumption so the issue isn't sunk.
// Everything else byte-identical to R22.
// ---------------------------------------------------------------------------

typedef _Float16 half2v __attribute__((ext_vector_type(2)));
typedef decltype(__builtin_amdgcn_cvt_pkrtz(0.f, 0.f)) f16x2b;  // builtin-native v2f16

#define PINU(v) asm volatile("" : "+v"(v))

#if defined(__has_builtin)
#if __has_builtin(__builtin_amdgcn_fdot2)
#define HAVE_FDOT2 1
#endif
#endif

#ifdef HAVE_FDOT2
__device__ __forceinline__ float dot2f(unsigned h, unsigned w, float c) {
    return __builtin_amdgcn_fdot2(__builtin_bit_cast(f16x2b, h),
                                  __builtin_bit_cast(f16x2b, w), c, false);
}
#else
__device__ __forceinline__ float dot2f(unsigned h, unsigned w, float c) {
    half2v a = __builtin_bit_cast(half2v, h);
    half2v b = __builtin_bit_cast(half2v, w);
    c = fmaf((float)a[0], (float)b[0], c);
    c = fmaf((float)a[1], (float)b[1], c);
    return c;
}
#endif

// Full-wave sum via DPP adds (VALU pipe; validated R14-R22). Result in lane 63.
__device__ __forceinline__ float wave_sum64_dpp(float v) {
    int x;
    x = __builtin_amdgcn_update_dpp(0, __float_as_int(v), 0x111, 0xf, 0xf, false); v += __int_as_float(x);
    x = __builtin_amdgcn_update_dpp(0, __float_as_int(v), 0x112, 0xf, 0xf, false); v += __int_as_float(x);
    x = __builtin_amdgcn_update_dpp(0, __float_as_int(v), 0x114, 0xf, 0xf, false); v += __int_as_float(x);
    x = __builtin_amdgcn_update_dpp(0, __float_as_int(v), 0x118, 0xf, 0xf, false); v += __int_as_float(x);
    x = __builtin_amdgcn_update_dpp(0, __float_as_int(v), 0x142, 0xa, 0xf, false); v += __int_as_float(x);
    x = __builtin_amdgcn_update_dpp(0, __float_as_int(v), 0x143, 0xc, 0xf, false); v += __int_as_float(x);
    return v;
}

__device__ __forceinline__ float sigm(float x) { return 1.f / (1.f + __expf(-x)); }
__device__ __forceinline__ float fast_tanh(float x) {
    float t = __expf(-2.f * fabsf(x));
    float r = (1.f - t) / (1.f + t);
    return copysignf(r, x);
}

// h transport: single-instruction RTZ pack (proven R17-R22 numerics)
__device__ __forceinline__ unsigned pack_h(float a, float b) {
    auto p = __builtin_amdgcn_cvt_pkrtz(a, b);
    return __builtin_bit_cast(unsigned, p);
}
// weight packing (init-only): RNE, matches the old pack_f16 kernel exactly
__device__ __forceinline__ unsigned pack_rne(float a, float b) {
    return (unsigned)__half_as_ushort(__float2half(a)) |
           ((unsigned)__half_as_ushort(__float2half(b)) << 16);
}

__device__ __forceinline__ unsigned agent_loadu(const unsigned* p) {
    return __hip_atomic_load(const_cast<unsigned*>(p), __ATOMIC_RELAXED,
                             __HIP_MEMORY_SCOPE_AGENT);
}
__device__ __forceinline__ void agent_storeu(unsigned* p, unsigned v) {
    __hip_atomic_store(p, v, __ATOMIC_RELAXED, __HIP_MEMORY_SCOPE_AGENT);
}
__device__ __forceinline__ float agent_loadf(const float* p) {
    return __hip_atomic_load(const_cast<float*>(p), __ATOMIC_RELAXED,
                             __HIP_MEMORY_SCOPE_AGENT);
}
__device__ __forceinline__ void agent_storef(float* p, float v) {
    __hip_atomic_store(p, v, __ATOMIC_RELAXED, __HIP_MEMORY_SCOPE_AGENT);
}
__device__ __forceinline__ bool isp(float v) { return __float_as_uint(v) == POISON_U; }

// Software grid barrier (coop launch => all WGs resident). ACQ_REL arrive
// orders prior agent stores; ACQUIRE spin pairs with it. Valve: never hangs.
__device__ __forceinline__ void grid_barrier(int* bar, int idx, int tid) {
    __syncthreads();
    if (tid == 0) {
        __hip_atomic_fetch_add(&bar[idx], 1, __ATOMIC_ACQ_REL,
                               __HIP_MEMORY_SCOPE_AGENT);
        for (int it = 0; it < SPIN_MAX; ++it) {
            if (__hip_atomic_load(&bar[idx], __ATOMIC_ACQUIRE,
                                  __HIP_MEMORY_SCOPE_AGENT) >= NWG_TOT) break;
            __builtin_amdgcn_s_sleep(2);
        }
    }
    __syncthreads();
}

// ---------------------------------------------------------------------------
// In-kernel GEMM tile (256-thread team): G[t0..t0+63][n0..n0+63] =
// concat(x,time)[t] . Wih1[n] + bih1[n] + bhh1[n].  Agent-scope stores.
// Pad +4 (stride 68): 16B-aligned rows -> ds_read_b128 (R19-proven layout).
// ---------------------------------------------------------------------------
#define BM 64
#define BN 64
#define BK 32
#define GK (INDIM + 1)   // 513

__device__ __forceinline__ void gemm_tile(
    int bm, int bn, int ttid,
    const float* __restrict__ B, const float* __restrict__ bias1,
    const float* __restrict__ bias2, float* C,
    const float* __restrict__ x, const float* __restrict__ timev,
    float (*As)[BM + 4], float (*Bs)[BN + 4])
{
    const int t0 = bm * BM;
    const int n0 = bn * BN;
    const int tx = ttid & 15;
    const int ty = ttid >> 4;

    float acc[4][4] = {{0.f}};

    for (int kc = 0; kc < GK; kc += BK) {
#pragma unroll
        for (int i = 0; i < 8; i++) {
            int idx = ttid + i * 256;
            int r = idx >> 5;
            int c = idx & 31;
            int col = kc + c;
            int trow = t0 + r;
            float av = (col < INDIM) ? x[(size_t)trow * INDIM + col]
                                     : ((col == INDIM) ? timev[trow] : 0.f);
            As[c][r] = av;
            int nrow = n0 + r;
            Bs[c][r] = (col < GK) ? B[(size_t)nrow * GK + col] : 0.f;
        }
        __syncthreads();

#pragma unroll
        for (int kk = 0; kk < BK; kk++) {
            float a[4], b[4];
#pragma unroll
            for (int i = 0; i < 4; i++) a[i] = As[kk][ty * 4 + i];
#pragma unroll
            for (int j = 0; j < 4; j++) b[j] = Bs[kk][tx * 4 + j];
#pragma unroll
            for (int i = 0; i < 4; i++)
#pragma unroll
                for (int j = 0; j < 4; j++)
                    acc[i][j] = fmaf(a[i], b[j], acc[i][j]);
        }
        __syncthreads();
    }

#pragma unroll
    for (int i = 0; i < 4; i++) {
        int trow = t0 + ty * 4 + i;
#pragma unroll
        for (int j = 0; j < 4; j++) {
            int n = n0 + tx * 4 + j;
            agent_storef(C + (size_t)trow * NGATE + n,
                         acc[i][j] + bias1[n] + bias2[n]);
        }
    }
}

// ---------------------------------------------------------------------------
// Fused: G-GEMM (L23 WGs) + 3-layer dataflow scan + attention tail.
// H rows: packed f16 pairs, 512 uints/row. Weight uint j = cols (2j,2j+1);
// lane s handles uint indices s+64m, m=0..7 -> LDS reads shp[s+64m].
// Weights packed ON LOAD (RNE) from fp32 cols (2s+128m, 2s+128m+1).
// L1 (wg<64): 16 units/WG, wave q owns unit u0+q; polls in-kernel G.
// L23 (wg>=64): GEMM phase (4 teams x 2 tiles, t-major), then scan.
// R23: h2/h3 loads EARLY-ISSUED after barrier A1 (RT overlaps phase-1 dots);
// phase 2 validates with the predicated spin.
// Tail: barrier -> attn dots -> barrier -> fused softmax+context.
// ---------------------------------------------------------------------------
__global__ __launch_bounds__(1024, 4) void fused_scan(
    const float* __restrict__ Whh1,       // fp32 weights (packed on load)
    float* G1,                            // fp32 gate inputs (poisoned; GEMM'd here)
    const float* __restrict__ Wih2,
    const float* __restrict__ Whh2,
    const float* __restrict__ Wih1,       // fp32 Wih1 (GEMM operand)
    const float* __restrict__ bih1, const float* __restrict__ bhh1,
    const float* __restrict__ xin, const float* __restrict__ timev,
    const float* bih2, const float* bhh2,
    const float* h0_1, const float* c0_1,
    const float* h0_2, const float* c0_2,
    const float* h0_3, const float* c0_3,
    unsigned* H1p, unsigned* H2p, unsigned* H3p,  // packed h rows, poisoned
    float* H3f,                                   // fp32 h3 (agent stores)
    float* attnb, float* outp, int* bar)          // attention buf, output, barriers
{
    __shared__ unsigned shp1[512];
    __shared__ unsigned shp2[512];
    __shared__ unsigned shp3[512];
    __shared__ float gbuf[16][4];  // L1: [unit][gate]; L23: 0-7 L2, 8-15 L3
    __shared__ float AsT[4][BK][BM + 4];   // GEMM team buffers (L23, phase 0)
    __shared__ float BsT[4][BK][BN + 4];

    const int tid = threadIdx.x;
    const int wg  = blockIdx.x;
    const int q   = tid >> 6;      // wave 0..15
    const int s   = tid & 63;

    if (wg < NWG_L1) {
        // ------- Layer 1: WG owns 16 units, wave q owns unit u0+q -------
        const int u0 = wg << 4;
        const int u  = u0 + q;
        unsigned w[4][8];
#pragma unroll
        for (int g = 0; g < 4; ++g) {
            const float* row = Whh1 + (size_t)((g << 10) + u) * 1024 + 2 * s;
#pragma unroll
            for (int m = 0; m < 8; ++m) {
                float2 v = *(const float2*)(row + 128 * m);
                w[g][m] = pack_rne(v.x, v.y);
            }
        }
        float c1 = (tid < 16) ? c0_1[u0 + tid] : 0.f;
        unsigned pv = 0u;   // cross-iteration prefetch of the h1 row

        for (int t = 0; t < TSTEPS; ++t) {
#pragma unroll
            for (int g = 0; g < 4; ++g)
#pragma unroll
                for (int m = 0; m < 8; ++m) PINU(w[g][m]);

            float Gv0 = 0.f, Gv1 = 0.f, Gv2 = 0.f, Gv3 = 0.f;
            if (tid < 16) {   // prefetch gate inputs (agent: in-kernel producer)
                const float* gptr = G1 + (size_t)t * NGATE + u0 + tid;
                Gv0 = agent_loadf(gptr);
                Gv1 = agent_loadf(gptr + 1024);
                Gv2 = agent_loadf(gptr + 2048);
                Gv3 = agent_loadf(gptr + 3072);
            }
            // stage packed h1[t-1]: check prefetched value, spin-fix misses
            if (tid < 512) {
                if (t == 0) {
                    shp1[tid] = pack_h(h0_1[2 * tid], h0_1[2 * tid + 1]);
                } else {
                    const unsigned* p = H1p + (size_t)(t - 1) * 512 + tid;
                    unsigned v = pv;
                    for (int it = 0; it < SPIN_MAX; ++it) {
                        if (__ballot(v == POISON_U) == 0ULL) break;
                        __builtin_amdgcn_s_sleep(1);
                        if (v == POISON_U) v = agent_loadu(p);
                    }
                    shp1[tid] = v;
                }
            }
            __syncthreads();                                   // A: staged

            float a0 = 0.f, a1 = 0.f, a2 = 0.f, a3 = 0.f;
#pragma unroll
            for (int m = 0; m < 8; ++m) {
                unsigned hu = shp1[s + 64 * m];
                a0 = dot2f(hu, w[0][m], a0);
                a1 = dot2f(hu, w[1][m], a1);
                a2 = dot2f(hu, w[2][m], a2);
                a3 = dot2f(hu, w[3][m], a3);
            }
            a0 = wave_sum64_dpp(a0);
            a1 = wave_sum64_dpp(a1);
            a2 = wave_sum64_dpp(a2);
            a3 = wave_sum64_dpp(a3);
            if (s == 63) {
                gbuf[q][0] = a0;
                gbuf[q][1] = a1;
                gbuf[q][2] = a2;
                gbuf[q][3] = a3;
            }
            __syncthreads();                                   // B: sums ready

            if (tid < 16) {
                // validate G (in-kernel GEMM producer); huge slack after t>~40
                const float* gptr = G1 + (size_t)t * NGATE + u0 + tid;
                for (int it = 0; it < SPIN_MAX; ++it) {
                    if (__ballot(isp(Gv0) | isp(Gv1) | isp(Gv2) | isp(Gv3)) == 0ULL)
                        break;
                    __builtin_amdgcn_s_sleep(1);
                    if (isp(Gv0)) Gv0 = agent_loadf(gptr);
                    if (isp(Gv1)) Gv1 = agent_loadf(gptr + 1024);
                    if (isp(Gv2)) Gv2 = agent_loadf(gptr + 2048);
                    if (isp(Gv3)) Gv3 = agent_loadf(gptr + 3072);
                }
                float gi = gbuf[tid][0] + Gv0;
                float gf = gbuf[tid][1] + Gv1;
                float gg = gbuf[tid][2] + Gv2;
                float go = gbuf[tid][3] + Gv3;
                float i_ = sigm(gi), f_ = sigm(gf), g_ = fast_tanh(gg), o_ = sigm(go);
                c1 = f_ * c1 + i_ * g_;
                float hn = o_ * fast_tanh(c1);
                float hnn = __shfl_down(hn, 1, 64);
                if (!(tid & 1))
                    agent_storeu(H1p + (size_t)t * 512 + (u0 >> 1) + (tid >> 1),
                                 pack_h(hn, hnn));
            }
            // cross-iteration prefetch: issue load of the row just produced
            if (tid < 512 && t < TSTEPS - 1) {
                pv = agent_loadu(H1p + (size_t)t * 512 + tid);
                PINU(pv);
            }
        }
    } else {
        // ---- GEMM phase: 4 teams x 256 threads, exactly 2 tiles each ----
        {
            const int team = tid >> 8;
            const int ttid = tid & 255;
            const int tg   = (wg - NWG_L1) * 4 + team;   // 0..511
#pragma unroll
            for (int r = 0; r < 2; ++r) {
                const int wk = tg + r * 512;
                gemm_tile(wk >> 6, wk & 63, ttid, Wih1, bih1, bhh1, G1,
                          xin, timev, AsT[team], BsT[team]);
            }
        }
        __syncthreads();

        // ---- Layers 2 & 3 (shared weights): WG owns 8 units ----
        const int ul = q >> 1;     // unit-local 0..7
        const int gp = q & 1;      // 0 -> gates (i,f), 1 -> gates (g,o)
        const int u0 = (wg - NWG_L1) << 3;
        const int u  = u0 + ul;
        unsigned wi[2][8], wh[2][8];
#pragma unroll
        for (int j = 0; j < 2; ++j) {
            const float* ri = Wih2 + (size_t)(((2 * gp + j) << 10) + u) * 1024 + 2 * s;
            const float* rh = Whh2 + (size_t)(((2 * gp + j) << 10) + u) * 1024 + 2 * s;
#pragma unroll
            for (int m = 0; m < 8; ++m) {
                float2 vi = *(const float2*)(ri + 128 * m);
                float2 vh = *(const float2*)(rh + 128 * m);
                wi[j][m] = pack_rne(vi.x, vi.y);
                wh[j][m] = pack_rne(vh.x, vh.y);
            }
        }
        float bias0 = 0.f, bias1v = 0.f, bias2v = 0.f, bias3 = 0.f, cst = 0.f;
        if (tid < 16) {
            int uu = u0 + (tid & 7);
            bias0  = bih2[uu]        + bhh2[uu];
            bias1v = bih2[1024 + uu] + bhh2[1024 + uu];
            bias2v = bih2[2048 + uu] + bhh2[2048 + uu];
            bias3  = bih2[3072 + uu] + bhh2[3072 + uu];
            cst = (tid < 8) ? c0_2[u0 + tid] : c0_3[u0 + tid - 8];
        }
        unsigned pv1 = 0u;  // cross-iteration prefetch of h1 row
        if (tid < 512) pv1 = agent_loadu(H1p + tid);   // prologue: row 0

        // iteration t: layer2 tick t (needs h1[t], h2[t-1]) and
        //              layer3 tick t-1 (needs h2[t-1], h3[t-2])
        for (int t = 0; t <= TSTEPS; ++t) {
#pragma unroll
            for (int j = 0; j < 2; ++j)
#pragma unroll
                for (int m = 0; m < 8; ++m) { PINU(wi[j][m]); PINU(wh[j][m]); }

            const bool do2 = (t < TSTEPS);
            const bool do3 = (t >= 1);

            // ---- phase 0: stage h1[t] (slack row, prefetched) ----
            if (tid < 512 && do2) {
                const unsigned* p = H1p + (size_t)t * 512 + tid;
                unsigned v = pv1;
                for (int it = 0; it < SPIN_MAX; ++it) {
                    if (__ballot(v == POISON_U) == 0ULL) break;
                    __builtin_amdgcn_s_sleep(1);
                    if (v == POISON_U) v = agent_loadu(p);
                }
                shp1[tid] = v;
            }
            __syncthreads();                                   // A1: h1 staged

            // ---- R23: EARLY-ISSUE h2[t-1]/h3[t-2] loads (RT overlaps dots)
            unsigned e2 = POISON_U, e3 = POISON_U;
            if (tid < 512) {
                if (t > 0)
                    e2 = agent_loadu(H2p + (size_t)(t - 1) * 512 + tid);
            } else {
                if (t > 1)
                    e3 = agent_loadu(H3p + (size_t)(t - 2) * 512 + (tid - 512));
            }

            // ---- phase 1: wi*h1 partial dots (overlap the early loads) ----
            float p20 = 0.f, p21 = 0.f;
#pragma unroll
            for (int m = 0; m < 8; ++m) {
                unsigned h1u = shp1[s + 64 * m];
                p20 = dot2f(h1u, wi[0][m], p20);
                p21 = dot2f(h1u, wi[1][m], p21);
            }
            PINU(e2); PINU(e3);   // anchor: wait for early loads HERE, not earlier

            // ---- phase 2: validate early loads; predicated spin-fix ----
            if (tid < 512) {
                if (t == 0) {
                    shp2[tid] = pack_h(h0_2[2 * tid], h0_2[2 * tid + 1]);
                } else {
                    const unsigned* p = H2p + (size_t)(t - 1) * 512 + tid;
                    unsigned v = e2;
                    for (int it = 0; it < SPIN_MAX; ++it) {
                        if (__ballot(v == POISON_U) == 0ULL) break;
                        __builtin_amdgcn_s_sleep(1);
                        if (v == POISON_U) v = agent_loadu(p);
                    }
                    shp2[tid] = v;
                }
            } else {
                const int sid = tid - 512;
                if (t == 1) {
                    shp3[sid] = pack_h(h0_3[2 * sid], h0_3[2 * sid + 1]);
                } else if (t > 1) {
                    const unsigned* p = H3p + (size_t)(t - 2) * 512 + sid;
                    unsigned v = e3;
                    for (int it = 0; it < SPIN_MAX; ++it) {
                        if (__ballot(v == POISON_U) == 0ULL) break;
                        __builtin_amdgcn_s_sleep(1);
                        if (v == POISON_U) v = agent_loadu(p);
                    }
                    shp3[sid] = v;
                }
            }
            __syncthreads();                                   // A2: h2/h3 staged

            // ---- phase 3: remaining dots (single block, proven shape) ----
            float p30 = 0.f, p31 = 0.f;
#pragma unroll
            for (int m = 0; m < 8; ++m) {
                unsigned h2u = shp2[s + 64 * m];
                unsigned h3u = shp3[s + 64 * m];
                p20 = dot2f(h2u, wh[0][m], p20);
                p21 = dot2f(h2u, wh[1][m], p21);
                p30 = dot2f(h2u, wi[0][m], p30);
                p31 = dot2f(h2u, wi[1][m], p31);
                p30 = dot2f(h3u, wh[0][m], p30);
                p31 = dot2f(h3u, wh[1][m], p31);
            }
            float s20 = wave_sum64_dpp(p20);
            float s21 = wave_sum64_dpp(p21);
            float s30 = wave_sum64_dpp(p30);
            float s31 = wave_sum64_dpp(p31);
            if (s == 63) {
                gbuf[ul][2 * gp]          = s20;
                gbuf[ul][2 * gp + 1]      = s21;
                gbuf[8 + ul][2 * gp]      = s30;
                gbuf[8 + ul][2 * gp + 1]  = s31;
            }
            __syncthreads();                                   // B: sums ready

            if (tid < 16) {
                const bool act = (tid < 8) ? do2 : do3;
                float hn = 0.f;
                if (act) {
                    float gi = gbuf[tid][0] + bias0;
                    float gf = gbuf[tid][1] + bias1v;
                    float gg = gbuf[tid][2] + bias2v;
                    float go = gbuf[tid][3] + bias3;
                    float i_ = sigm(gi), f_ = sigm(gf), g_ = fast_tanh(gg), o_ = sigm(go);
                    cst = f_ * cst + i_ * g_;
                    hn = o_ * fast_tanh(cst);
                }
                float hnn = __shfl_down(hn, 1, 64);
                if (act) {
                    if (tid < 8) {         // h2 units: packed store (4 uints/WG)
                        if (!(tid & 1))
                            agent_storeu(H2p + (size_t)t * 512 + (u0 >> 1) + (tid >> 1),
                                         pack_h(hn, hnn));
                    } else {               // h3 units: packed + fp32 for attn
                        if (!(tid & 1))
                            agent_storeu(H3p + (size_t)(t - 1) * 512 + (u0 >> 1) + ((tid - 8) >> 1),
                                         pack_h(hn, hnn));
                        agent_storef(H3f + (size_t)(t - 1) * HDIM + u0 + (tid - 8), hn);
                    }
                }
            }
            // cross-iteration prefetch of h1[t+1]
            if (tid < 512 && t < TSTEPS - 1) {
                pv1 = agent_loadu(H1p + (size_t)(t + 1) * 512 + tid);
                PINU(pv1);
            }
        }
    }

    // ------------------- attention tail (all 192 WGs) -------------------
    const int gw = wg * 16 + q;    // global wave id, 0..3071
    grid_barrier(bar, 0, tid);     // H3f complete + visible

    if (gw < TSTEPS) {             // attn[t] = h3[t] . h3[T-1]
        const float* hrow = H3f + (size_t)gw * HDIM;
        const float* hf   = H3f + (size_t)(TSTEPS - 1) * HDIM;
        float p = 0.f;
#pragma unroll
        for (int j = 0; j < 16; ++j) {
            int k = s + 64 * j;
            p = fmaf(agent_loadf(hrow + k), agent_loadf(hf + k), p);
        }
        p = wave_sum64_dpp(p);
        if (s == 63) agent_storef(attnb + gw, p);
    }
    grid_barrier(bar, 1, tid);     // attn complete

    if (gw < HDIM) {               // fused softmax+context (per-wave stats)
        float av[16];
        float m = -1e30f;
#pragma unroll
        for (int j = 0; j < 16; ++j) {
            av[j] = agent_loadf(attnb + s + 64 * j);
            m = fmaxf(m, av[j]);
        }
#pragma unroll
        for (int d = 32; d; d >>= 1) m = fmaxf(m, __shfl_xor(m, d, 64));
        float S = 0.f, p = 0.f;
#pragma unroll
        for (int j = 0; j < 16; ++j) {
            int t = s + 64 * j;
            float e = __expf(av[j] - m);
            S += e;
            p = fmaf(e, agent_loadf(H3f + (size_t)t * HDIM + gw), p);
        }
        S = wave_sum64_dpp(S);
        p = wave_sum64_dpp(p);
        if (s == 63) outp[gw] = p / S;
    }
}

// ---------------------------------------------------------------------------
// Launch
// ---------------------------------------------------------------------------
extern "C" void kernel_launch(void* const* d_in, const int* in_sizes, int n_in,
                              void* d_out, int out_size, void* d_ws, size_t ws_size,
                              hipStream_t stream)
{
    const float* x     = (const float*)d_in[0];
    const float* timev = (const float*)d_in[1];
    const float* h0_1  = (const float*)d_in[2];
    const float* c0_1  = (const float*)d_in[3];
    const float* h0_2  = (const float*)d_in[4];
    const float* c0_2  = (const float*)d_in[5];
    const float* h0_3  = (const float*)d_in[6];
    const float* c0_3  = (const float*)d_in[7];
    const float* Wih1  = (const float*)d_in[8];
    const float* Whh1  = (const float*)d_in[9];
    const float* bih1  = (const float*)d_in[10];
    const float* bhh1  = (const float*)d_in[11];
    const float* Wih2  = (const float*)d_in[12];
    const float* Whh2  = (const float*)d_in[13];
    const float* bih2  = (const float*)d_in[14];
    const float* bhh2  = (const float*)d_in[15];

    // workspace carve (~27 MB)
    float* G      = (float*)d_ws;                             // 1024*4096 fp32
    unsigned* H1p = (unsigned*)(G + (size_t)TSTEPS * NGATE);  // 1024*512 uints
    unsigned* H2p = H1p + (size_t)TSTEPS * 512;
    unsigned* H3p = H2p + (size_t)TSTEPS * 512;
    float* H3f    = (float*)(H3p + (size_t)TSTEPS * 512);     // 1024*1024 fp32
    float* attnb  = H3f + (size_t)TSTEPS * HDIM;              // 1024 fp32
    int* bar      = (int*)(attnb + 1024);                     // 16 ints
    float* out    = (float*)d_out;

    // Poison G + packed H rows (contiguous); zero the barrier counters.
    hipMemsetAsync(G, 0x7C,
                   (size_t)TSTEPS * NGATE * sizeof(float) +
                   (size_t)3 * TSTEPS * 512 * sizeof(unsigned), stream);
    hipMemsetAsync(bar, 0, 16 * sizeof(int), stream);

    // Fused GEMM + scan + attention (cooperative: 192 WGs x 1024 threads)
    {
        const float* a0 = Whh1;  float* a1 = G;
        const float* a2 = Wih2;  const float* a3 = Whh2;
        const float* a4 = Wih1;  const float* a5 = bih1;  const float* a6 = bhh1;
        const float* a7 = x;     const float* a8 = timev;
        const float* a9 = bih2;  const float* a10 = bhh2;
        const float* a11 = h0_1; const float* a12 = c0_1;
        const float* a13 = h0_2; const float* a14 = c0_2;
        const float* a15 = h0_3; const float* a16 = c0_3;
        unsigned* a17 = H1p; unsigned* a18 = H2p; unsigned* a19 = H3p;
        float* a20 = H3f; float* a21 = attnb; float* a22 = out; int* a23 = bar;
        void* args[] = {&a0,&a1,&a2,&a3,&a4,&a5,&a6,&a7,&a8,&a9,&a10,&a11,
                        &a12,&a13,&a14,&a15,&a16,&a17,&a18,&a19,&a20,&a21,
                        &a22,&a23};
        hipLaunchCooperativeKernel((void*)fused_scan, dim3(NWG_TOT), dim3(1024),
                                   args, 0, stream);
    }
}

// Round 13
// 2791.972 us; speedup vs baseline: 1.0415x; 1.0415x over previous
//
#include <hip/hip_runtime.h>
#include <hip/hip_fp16.h>

// Problem constants
#define TSTEPS 1024
#define HDIM   1024
#define INDIM  512
#define NGATE  4096     // 4*HDIM
#define NWG_L1  64
#define NWG_L23 128
#define NWG_TOT 192     // proven coop envelope
#define POISON_U 0x7C7C7C7Cu   // f16-pair poison; as f32 = 5.2e36 (unreachable)
#define SPIN_MAX (1 << 20)     // deadlock valve: fail loud, never hang

// ---------------------------------------------------------------------------
// R23 post-mortem: early-issue NULL (scan 2830 ~ R22's 2800) -> phase-2 RT
// was already hidden; cadence is the store->visible->catch cycle over 64
// producer WGs (protocol floor). Fused variants R20-R23 (2891/2996/2885/2908)
// never beat R19's 2784: the fused tail's agent-scope uncoalesced reads +
// in-kernel fp32 weight-pack init cost what the saved launches gained.
// R24 = EXACT R19 (best measured: 2784 total, scan 2643) with ONE delta:
// softmax fused into context_kernel (R22-validated per-wave-stats math,
// plain cached loads; kernel boundary orders attnb). One fewer launch.
// If this reproduces ~2770 +/- 20 -> declare roofline.
// ---------------------------------------------------------------------------

typedef _Float16 half2v __attribute__((ext_vector_type(2)));
typedef decltype(__builtin_amdgcn_cvt_pkrtz(0.f, 0.f)) f16x2b;  // builtin-native v2f16

#define PINU(v) asm volatile("" : "+v"(v))

#if defined(__has_builtin)
#if __has_builtin(__builtin_amdgcn_fdot2)
#define HAVE_FDOT2 1
#endif
#endif

#ifdef HAVE_FDOT2
// one v_dot2_f32_f16 per packed pair (fp32 accumulate)
__device__ __forceinline__ float dot2f(unsigned h, unsigned w, float c) {
    return __builtin_amdgcn_fdot2(__builtin_bit_cast(f16x2b, h),
                                  __builtin_bit_cast(f16x2b, w), c, false);
}
#else
// fallback: 2x v_fma_mix (R14-R18 validated)
__device__ __forceinline__ float dot2f(unsigned h, unsigned w, float c) {
    half2v a = __builtin_bit_cast(half2v, h);
    half2v b = __builtin_bit_cast(half2v, w);
    c = fmaf((float)a[0], (float)b[0], c);
    c = fmaf((float)a[1], (float)b[1], c);
    return c;
}
#endif

// Full-wave sum via DPP adds (VALU pipe; validated R14-R23). Result in lane 63.
__device__ __forceinline__ float wave_sum64_dpp(float v) {
    int x;
    x = __builtin_amdgcn_update_dpp(0, __float_as_int(v), 0x111, 0xf, 0xf, false); v += __int_as_float(x);
    x = __builtin_amdgcn_update_dpp(0, __float_as_int(v), 0x112, 0xf, 0xf, false); v += __int_as_float(x);
    x = __builtin_amdgcn_update_dpp(0, __float_as_int(v), 0x114, 0xf, 0xf, false); v += __int_as_float(x);
    x = __builtin_amdgcn_update_dpp(0, __float_as_int(v), 0x118, 0xf, 0xf, false); v += __int_as_float(x);
    x = __builtin_amdgcn_update_dpp(0, __float_as_int(v), 0x142, 0xa, 0xf, false); v += __int_as_float(x);
    x = __builtin_amdgcn_update_dpp(0, __float_as_int(v), 0x143, 0xc, 0xf, false); v += __int_as_float(x);
    return v;
}

__device__ __forceinline__ float sigm(float x) { return 1.f / (1.f + __expf(-x)); }
__device__ __forceinline__ float fast_tanh(float x) {
    float t = __expf(-2.f * fabsf(x));
    float r = (1.f - t) / (1.f + t);
    return copysignf(r, x);
}

__device__ __forceinline__ unsigned pack_h(float a, float b) {
    auto p = __builtin_amdgcn_cvt_pkrtz(a, b);
    return __builtin_bit_cast(unsigned, p);
}

__device__ __forceinline__ unsigned agent_loadu(const unsigned* p) {
    return __hip_atomic_load(const_cast<unsigned*>(p), __ATOMIC_RELAXED,
                             __HIP_MEMORY_SCOPE_AGENT);
}
__device__ __forceinline__ void agent_storeu(unsigned* p, unsigned v) {
    __hip_atomic_store(p, v, __ATOMIC_RELAXED, __HIP_MEMORY_SCOPE_AGENT);
}
__device__ __forceinline__ float agent_loadf(const float* p) {
    return __hip_atomic_load(const_cast<float*>(p), __ATOMIC_RELAXED,
                             __HIP_MEMORY_SCOPE_AGENT);
}
__device__ __forceinline__ void agent_storef(float* p, float v) {
    __hip_atomic_store(p, v, __ATOMIC_RELAXED, __HIP_MEMORY_SCOPE_AGENT);
}
__device__ __forceinline__ bool isp(float v) { return __float_as_uint(v) == POISON_U; }

// ---------------------------------------------------------------------------
// Prep: pack fp32 matrix (rows x 1024) into f16-pair uints (rows x 512), RNE.
// ---------------------------------------------------------------------------
__global__ __launch_bounds__(256) void pack_f16(
    const float* __restrict__ src, unsigned* __restrict__ dst, int n)
{
    int i = blockIdx.x * 256 + threadIdx.x;
    if (i < n) {
        float2 v = *(const float2*)(src + 2 * (size_t)i);
        dst[i] = (unsigned)__half_as_ushort(__float2half(v.x)) |
                 ((unsigned)__half_as_ushort(__float2half(v.y)) << 16);
    }
}

// ---------------------------------------------------------------------------
// In-kernel GEMM tile (256-thread team): G[t0..t0+63][n0..n0+63] =
// concat(x,time)[t] . Wih1[n] + bih1[n] + bhh1[n].  Agent-scope stores.
// Pad +4 (stride 68): 16B-aligned rows -> ds_read_b128 (R19-proven layout).
// ---------------------------------------------------------------------------
#define BM 64
#define BN 64
#define BK 32
#define GK (INDIM + 1)   // 513

__device__ __forceinline__ void gemm_tile(
    int bm, int bn, int ttid,
    const float* __restrict__ B, const float* __restrict__ bias1,
    const float* __restrict__ bias2, float* C,
    const float* __restrict__ x, const float* __restrict__ timev,
    float (*As)[BM + 4], float (*Bs)[BN + 4])
{
    const int t0 = bm * BM;
    const int n0 = bn * BN;
    const int tx = ttid & 15;
    const int ty = ttid >> 4;

    float acc[4][4] = {{0.f}};

    for (int kc = 0; kc < GK; kc += BK) {
#pragma unroll
        for (int i = 0; i < 8; i++) {
            int idx = ttid + i * 256;
            int r = idx >> 5;
            int c = idx & 31;
            int col = kc + c;
            int trow = t0 + r;
            float av = (col < INDIM) ? x[(size_t)trow * INDIM + col]
                                     : ((col == INDIM) ? timev[trow] : 0.f);
            As[c][r] = av;
            int nrow = n0 + r;
            Bs[c][r] = (col < GK) ? B[(size_t)nrow * GK + col] : 0.f;
        }
        __syncthreads();

#pragma unroll
        for (int kk = 0; kk < BK; kk++) {
            float a[4], b[4];
#pragma unroll
            for (int i = 0; i < 4; i++) a[i] = As[kk][ty * 4 + i];
#pragma unroll
            for (int j = 0; j < 4; j++) b[j] = Bs[kk][tx * 4 + j];
#pragma unroll
            for (int i = 0; i < 4; i++)
#pragma unroll
                for (int j = 0; j < 4; j++)
                    acc[i][j] = fmaf(a[i], b[j], acc[i][j]);
        }
        __syncthreads();
    }

#pragma unroll
    for (int i = 0; i < 4; i++) {
        int trow = t0 + ty * 4 + i;
#pragma unroll
        for (int j = 0; j < 4; j++) {
            int n = n0 + tx * 4 + j;
            agent_storef(C + (size_t)trow * NGATE + n,
                         acc[i][j] + bias1[n] + bias2[n]);
        }
    }
}

// ---------------------------------------------------------------------------
// Fused dataflow 3-layer scan (R19 structure, exact).
// H rows: packed f16 pairs, 512 uints/row. Weight uint j = cols (2j,2j+1);
// lane s handles uint indices s+64m, m=0..7 -> LDS reads shp[s+64m].
// L1 (wg<64): 16 units/WG, wave q owns unit u0+q (all 4 gates, 32 uints);
//   G rows are POLLED (produced in-kernel by L23's GEMM phase).
// L23 (wg>=64): GEMM phase first (4 teams x 2 tiles, t-major order), then
//   scan: 8 units/WG, wave q owns unit u0+(q>>1), gate pair q&1, both layers.
// ---------------------------------------------------------------------------
__global__ __launch_bounds__(1024, 4) void fused_scan(
    const unsigned* __restrict__ Wp1,     // packed Whh1, 4096 x 512
    float* G1,                            // fp32 gate inputs (poisoned; GEMM'd here)
    const unsigned* __restrict__ Wpi2,    // packed Wih2
    const unsigned* __restrict__ Wph2,    // packed Whh2
    const float* __restrict__ Wih1,       // fp32 Wih1 (GEMM operand)
    const float* __restrict__ bih1, const float* __restrict__ bhh1,
    const float* __restrict__ xin, const float* __restrict__ timev,
    const float* bih2, const float* bhh2,
    const float* h0_1, const float* c0_1,
    const float* h0_2, const float* c0_2,
    const float* h0_3, const float* c0_3,
    unsigned* H1p, unsigned* H2p, unsigned* H3p,  // packed h rows, poisoned
    float* H3f)                                   // fp32 h3 for attention
{
    __shared__ unsigned shp1[512];
    __shared__ unsigned shp2[512];
    __shared__ unsigned shp3[512];
    __shared__ float gbuf[16][4];  // L1: [unit][gate]; L23: 0-7 L2, 8-15 L3
    __shared__ float AsT[4][BK][BM + 4];   // GEMM team buffers (L23, phase 0)
    __shared__ float BsT[4][BK][BN + 4];

    const int tid = threadIdx.x;
    const int wg  = blockIdx.x;
    const int q   = tid >> 6;      // wave 0..15
    const int s   = tid & 63;

    if (wg < NWG_L1) {
        // ------- Layer 1: WG owns 16 units, wave q owns unit u0+q -------
        const int u0 = wg << 4;
        const int u  = u0 + q;
        unsigned w[4][8];
#pragma unroll
        for (int g = 0; g < 4; ++g) {
            const unsigned* row = Wp1 + (size_t)((g << 10) + u) * 512 + s;
#pragma unroll
            for (int m = 0; m < 8; ++m)
                w[g][m] = row[64 * m];
        }
        float c1 = (tid < 16) ? c0_1[u0 + tid] : 0.f;
        unsigned pv = 0u;   // cross-iteration prefetch of the h1 row

        for (int t = 0; t < TSTEPS; ++t) {
#pragma unroll
            for (int g = 0; g < 4; ++g)
#pragma unroll
                for (int m = 0; m < 8; ++m) PINU(w[g][m]);

            float Gv0 = 0.f, Gv1 = 0.f, Gv2 = 0.f, Gv3 = 0.f;
            if (tid < 16) {   // prefetch gate inputs (agent: in-kernel producer)
                const float* gptr = G1 + (size_t)t * NGATE + u0 + tid;
                Gv0 = agent_loadf(gptr);
                Gv1 = agent_loadf(gptr + 1024);
                Gv2 = agent_loadf(gptr + 2048);
                Gv3 = agent_loadf(gptr + 3072);
            }
            // stage packed h1[t-1]: check prefetched value, spin-fix misses
            if (tid < 512) {
                if (t == 0) {
                    shp1[tid] = pack_h(h0_1[2 * tid], h0_1[2 * tid + 1]);
                } else {
                    const unsigned* p = H1p + (size_t)(t - 1) * 512 + tid;
                    unsigned v = pv;
                    for (int it = 0; it < SPIN_MAX; ++it) {
                        if (__ballot(v == POISON_U) == 0ULL) break;
                        __builtin_amdgcn_s_sleep(1);
                        if (v == POISON_U) v = agent_loadu(p);
                    }
                    shp1[tid] = v;
                }
            }
            __syncthreads();                                   // A: staged

            float a0 = 0.f, a1 = 0.f, a2 = 0.f, a3 = 0.f;
#pragma unroll
            for (int m = 0; m < 8; ++m) {
                unsigned hu = shp1[s + 64 * m];
                a0 = dot2f(hu, w[0][m], a0);
                a1 = dot2f(hu, w[1][m], a1);
                a2 = dot2f(hu, w[2][m], a2);
                a3 = dot2f(hu, w[3][m], a3);
            }
            a0 = wave_sum64_dpp(a0);
            a1 = wave_sum64_dpp(a1);
            a2 = wave_sum64_dpp(a2);
            a3 = wave_sum64_dpp(a3);
            if (s == 63) {
                gbuf[q][0] = a0;
                gbuf[q][1] = a1;
                gbuf[q][2] = a2;
                gbuf[q][3] = a3;
            }
            __syncthreads();                                   // B: sums ready

            if (tid < 16) {
                // validate G (in-kernel GEMM producer); huge slack after t>~40
                const float* gptr = G1 + (size_t)t * NGATE + u0 + tid;
                for (int it = 0; it < SPIN_MAX; ++it) {
                    if (__ballot(isp(Gv0) | isp(Gv1) | isp(Gv2) | isp(Gv3)) == 0ULL)
                        break;
                    __builtin_amdgcn_s_sleep(1);
                    if (isp(Gv0)) Gv0 = agent_loadf(gptr);
                    if (isp(Gv1)) Gv1 = agent_loadf(gptr + 1024);
                    if (isp(Gv2)) Gv2 = agent_loadf(gptr + 2048);
                    if (isp(Gv3)) Gv3 = agent_loadf(gptr + 3072);
                }
                float gi = gbuf[tid][0] + Gv0;
                float gf = gbuf[tid][1] + Gv1;
                float gg = gbuf[tid][2] + Gv2;
                float go = gbuf[tid][3] + Gv3;
                float i_ = sigm(gi), f_ = sigm(gf), g_ = fast_tanh(gg), o_ = sigm(go);
                c1 = f_ * c1 + i_ * g_;
                float hn = o_ * fast_tanh(c1);
                float hnn = __shfl_down(hn, 1, 64);
                if (!(tid & 1))
                    agent_storeu(H1p + (size_t)t * 512 + (u0 >> 1) + (tid >> 1),
                                 pack_h(hn, hnn));
            }
            // cross-iteration prefetch: issue load of the row just produced
            if (tid < 512 && t < TSTEPS - 1) {
                pv = agent_loadu(H1p + (size_t)t * 512 + tid);
                PINU(pv);
            }
        }
    } else {
        // ---- GEMM phase: 4 teams x 256 threads, exactly 2 tiles each ----
        // work w in [0,1024): bm = w>>6 (t-block), bn = w&63 -> t-major
        // completion (G rows 0..511 after round 0). Fixed counts keep the
        // WG-wide __syncthreads aligned across teams.
        {
            const int team = tid >> 8;
            const int ttid = tid & 255;
            const int tg   = (wg - NWG_L1) * 4 + team;   // 0..511
#pragma unroll
            for (int r = 0; r < 2; ++r) {
                const int wk = tg + r * 512;
                gemm_tile(wk >> 6, wk & 63, ttid, Wih1, bih1, bhh1, G1,
                          xin, timev, AsT[team], BsT[team]);
            }
        }
        __syncthreads();

        // ---- Layers 2 & 3 (shared weights): WG owns 8 units ----
        const int ul = q >> 1;     // unit-local 0..7
        const int gp = q & 1;      // 0 -> gates (i,f), 1 -> gates (g,o)
        const int u0 = (wg - NWG_L1) << 3;
        const int u  = u0 + ul;
        unsigned wi[2][8], wh[2][8];
#pragma unroll
        for (int j = 0; j < 2; ++j) {
            const unsigned* ri = Wpi2 + (size_t)(((2 * gp + j) << 10) + u) * 512 + s;
            const unsigned* rh = Wph2 + (size_t)(((2 * gp + j) << 10) + u) * 512 + s;
#pragma unroll
            for (int m = 0; m < 8; ++m) {
                wi[j][m] = ri[64 * m];
                wh[j][m] = rh[64 * m];
            }
        }
        float bias0 = 0.f, bias1v = 0.f, bias2v = 0.f, bias3 = 0.f, cst = 0.f;
        if (tid < 16) {
            int uu = u0 + (tid & 7);
            bias0  = bih2[uu]        + bhh2[uu];
            bias1v = bih2[1024 + uu] + bhh2[1024 + uu];
            bias2v = bih2[2048 + uu] + bhh2[2048 + uu];
            bias3  = bih2[3072 + uu] + bhh2[3072 + uu];
            cst = (tid < 8) ? c0_2[u0 + tid] : c0_3[u0 + tid - 8];
        }
        unsigned pv1 = 0u;  // cross-iteration prefetch of h1 row
        if (tid < 512) pv1 = agent_loadu(H1p + tid);   // prologue: row 0

        // iteration t: layer2 tick t (needs h1[t], h2[t-1]) and
        //              layer3 tick t-1 (needs h2[t-1], h3[t-2])
        for (int t = 0; t <= TSTEPS; ++t) {
#pragma unroll
            for (int j = 0; j < 2; ++j)
#pragma unroll
                for (int m = 0; m < 8; ++m) { PINU(wi[j][m]); PINU(wh[j][m]); }

            const bool do2 = (t < TSTEPS);
            const bool do3 = (t >= 1);

            // ---- phase 0: stage h1[t] (slack row, prefetched) ----
            if (tid < 512 && do2) {
                const unsigned* p = H1p + (size_t)t * 512 + tid;
                unsigned v = pv1;
                for (int it = 0; it < SPIN_MAX; ++it) {
                    if (__ballot(v == POISON_U) == 0ULL) break;
                    __builtin_amdgcn_s_sleep(1);
                    if (v == POISON_U) v = agent_loadu(p);
                }
                shp1[tid] = v;
            }
            __syncthreads();                                   // A1: h1 staged

            // ---- phase 1: wi*h1 partial dots (overlaps peers' h2/h3 stores)
            float p20 = 0.f, p21 = 0.f;
#pragma unroll
            for (int m = 0; m < 8; ++m) {
                unsigned h1u = shp1[s + 64 * m];
                p20 = dot2f(h1u, wi[0][m], p20);
                p21 = dot2f(h1u, wi[1][m], p21);
            }

            // ---- phase 2: NOW poll the zero-slack rows h2[t-1], h3[t-2] ----
            if (tid < 512) {
                if (t == 0) {
                    shp2[tid] = pack_h(h0_2[2 * tid], h0_2[2 * tid + 1]);
                } else {
                    const unsigned* p = H2p + (size_t)(t - 1) * 512 + tid;
                    unsigned v = agent_loadu(p);
                    for (int it = 0; it < SPIN_MAX; ++it) {
                        if (__ballot(v == POISON_U) == 0ULL) break;
                        __builtin_amdgcn_s_sleep(1);
                        if (v == POISON_U) v = agent_loadu(p);
                    }
                    shp2[tid] = v;
                }
            } else {
                const int sid = tid - 512;
                if (t == 1) {
                    shp3[sid] = pack_h(h0_3[2 * sid], h0_3[2 * sid + 1]);
                } else if (t > 1) {
                    const unsigned* p = H3p + (size_t)(t - 2) * 512 + sid;
                    unsigned v = agent_loadu(p);
                    for (int it = 0; it < SPIN_MAX; ++it) {
                        if (__ballot(v == POISON_U) == 0ULL) break;
                        __builtin_amdgcn_s_sleep(1);
                        if (v == POISON_U) v = agent_loadu(p);
                    }
                    shp3[sid] = v;
                }
            }
            __syncthreads();                                   // A2: h2/h3 staged

            // ---- phase 3: remaining dots ----
            float p30 = 0.f, p31 = 0.f;
#pragma unroll
            for (int m = 0; m < 8; ++m) {
                unsigned h2u = shp2[s + 64 * m];
                unsigned h3u = shp3[s + 64 * m];
                p20 = dot2f(h2u, wh[0][m], p20);
                p21 = dot2f(h2u, wh[1][m], p21);
                p30 = dot2f(h2u, wi[0][m], p30);
                p31 = dot2f(h2u, wi[1][m], p31);
                p30 = dot2f(h3u, wh[0][m], p30);
                p31 = dot2f(h3u, wh[1][m], p31);
            }
            float s20 = wave_sum64_dpp(p20);
            float s21 = wave_sum64_dpp(p21);
            float s30 = wave_sum64_dpp(p30);
            float s31 = wave_sum64_dpp(p31);
            if (s == 63) {
                gbuf[ul][2 * gp]          = s20;
                gbuf[ul][2 * gp + 1]      = s21;
                gbuf[8 + ul][2 * gp]      = s30;
                gbuf[8 + ul][2 * gp + 1]  = s31;
            }
            __syncthreads();                                   // B: sums ready

            if (tid < 16) {
                const bool act = (tid < 8) ? do2 : do3;
                float hn = 0.f;
                if (act) {
                    float gi = gbuf[tid][0] + bias0;
                    float gf = gbuf[tid][1] + bias1v;
                    float gg = gbuf[tid][2] + bias2v;
                    float go = gbuf[tid][3] + bias3;
                    float i_ = sigm(gi), f_ = sigm(gf), g_ = fast_tanh(gg), o_ = sigm(go);
                    cst = f_ * cst + i_ * g_;
                    hn = o_ * fast_tanh(cst);
                }
                float hnn = __shfl_down(hn, 1, 64);
                if (act) {
                    if (tid < 8) {         // h2 units: packed store (4 uints/WG)
                        if (!(tid & 1))
                            agent_storeu(H2p + (size_t)t * 512 + (u0 >> 1) + (tid >> 1),
                                         pack_h(hn, hnn));
                    } else {               // h3 units: packed + fp32 for attn
                        if (!(tid & 1))
                            agent_storeu(H3p + (size_t)(t - 1) * 512 + (u0 >> 1) + ((tid - 8) >> 1),
                                         pack_h(hn, hnn));
                        H3f[(size_t)(t - 1) * HDIM + u0 + (tid - 8)] = hn;
                    }
                }
            }
            // cross-iteration prefetch of h1[t+1]
            if (tid < 512 && t < TSTEPS - 1) {
                pv1 = agent_loadu(H1p + (size_t)(t + 1) * 512 + tid);
                PINU(pv1);
            }
        }
    }
}

// ---------------------------------------------------------------------------
// Attention: dot kernel (unchanged R19), then fused softmax+context
// (R22-tail-validated math: same exp terms, division at the end).
// ---------------------------------------------------------------------------
__global__ __launch_bounds__(256) void attn_dot(
    const float* __restrict__ H3, float* __restrict__ attn)
{
    const int t = blockIdx.x * 4 + (threadIdx.x >> 6);
    const int lane = threadIdx.x & 63;
    const float* hrow = H3 + (size_t)t * HDIM;
    const float* hf = H3 + (size_t)(TSTEPS - 1) * HDIM;
    float p = 0.f;
    for (int j = lane; j < HDIM; j += 64) p = fmaf(hrow[j], hf[j], p);
#pragma unroll
    for (int d = 32; d; d >>= 1) p += __shfl_down(p, d, 64);
    if (lane == 0) attn[t] = p;
}

__global__ __launch_bounds__(256) void context_softmax_kernel(
    const float* __restrict__ H3, const float* __restrict__ attn,
    float* __restrict__ out)
{
    const int u = blockIdx.x * 4 + (threadIdx.x >> 6);
    const int lane = threadIdx.x & 63;
    float av[16];
    float m = -1e30f;
#pragma unroll
    for (int j = 0; j < 16; ++j) {
        av[j] = attn[lane + 64 * j];
        m = fmaxf(m, av[j]);
    }
#pragma unroll
    for (int d = 32; d; d >>= 1) m = fmaxf(m, __shfl_xor(m, d, 64));
    float S = 0.f, p = 0.f;
#pragma unroll
    for (int j = 0; j < 16; ++j) {
        int t = lane + 64 * j;
        float e = __expf(av[j] - m);
        S += e;
        p = fmaf(e, H3[(size_t)t * HDIM + u], p);
    }
#pragma unroll
    for (int d = 32; d; d >>= 1) {
        S += __shfl_xor(S, d, 64);
        p += __shfl_xor(p, d, 64);
    }
    if (lane == 0) out[u] = p / S;
}

// ---------------------------------------------------------------------------
// Launch
// ---------------------------------------------------------------------------
extern "C" void kernel_launch(void* const* d_in, const int* in_sizes, int n_in,
                              void* d_out, int out_size, void* d_ws, size_t ws_size,
                              hipStream_t stream)
{
    const float* x     = (const float*)d_in[0];
    const float* timev = (const float*)d_in[1];
    const float* h0_1  = (const float*)d_in[2];
    const float* c0_1  = (const float*)d_in[3];
    const float* h0_2  = (const float*)d_in[4];
    const float* c0_2  = (const float*)d_in[5];
    const float* h0_3  = (const float*)d_in[6];
    const float* c0_3  = (const float*)d_in[7];
    const float* Wih1  = (const float*)d_in[8];
    const float* Whh1  = (const float*)d_in[9];
    const float* bih1  = (const float*)d_in[10];
    const float* bhh1  = (const float*)d_in[11];
    const float* Wih2  = (const float*)d_in[12];
    const float* Whh2  = (const float*)d_in[13];
    const float* bih2  = (const float*)d_in[14];
    const float* bhh2  = (const float*)d_in[15];

    // workspace carve (~50 MB)
    float* G      = (float*)d_ws;                             // 1024*4096 fp32
    unsigned* H1p = (unsigned*)(G + (size_t)TSTEPS * NGATE);  // 1024*512 uints
    unsigned* H2p = H1p + (size_t)TSTEPS * 512;
    unsigned* H3p = H2p + (size_t)TSTEPS * 512;
    float* H3f    = (float*)(H3p + (size_t)TSTEPS * 512);     // 1024*1024 fp32
    float* attnb  = H3f + (size_t)TSTEPS * HDIM;              // 1024 fp32
    unsigned* Wp1  = (unsigned*)(attnb + 1024);               // 4096*512 uints each
    unsigned* Wpi2 = Wp1 + (size_t)NGATE * 512;
    unsigned* Wph2 = Wpi2 + (size_t)NGATE * 512;
    float* out  = (float*)d_out;

    // Poison G + packed H rows (contiguous): the poll protocol depends on it.
    hipMemsetAsync(G, 0x7C,
                   (size_t)TSTEPS * NGATE * sizeof(float) +
                   (size_t)3 * TSTEPS * 512 * sizeof(unsigned), stream);

    // Pack the three scan weight matrices to f16 pairs (one-time, RNE).
    {
        const int n = NGATE * 512;
        pack_f16<<<dim3(n / 256), dim3(256), 0, stream>>>(Whh1, Wp1, n);
        pack_f16<<<dim3(n / 256), dim3(256), 0, stream>>>(Wih2, Wpi2, n);
        pack_f16<<<dim3(n / 256), dim3(256), 0, stream>>>(Whh2, Wph2, n);
    }

    // Fused scan + in-kernel G-GEMM (cooperative: 192 WGs x 1024 threads)
    {
        const unsigned* a0 = Wp1;  float* a1 = G;
        const unsigned* a2 = Wpi2; const unsigned* a3 = Wph2;
        const float* a4 = Wih1;  const float* a5 = bih1;  const float* a6 = bhh1;
        const float* a7 = x;     const float* a8 = timev;
        const float* a9 = bih2;  const float* a10 = bhh2;
        const float* a11 = h0_1; const float* a12 = c0_1;
        const float* a13 = h0_2; const float* a14 = c0_2;
        const float* a15 = h0_3; const float* a16 = c0_3;
        unsigned* a17 = H1p; unsigned* a18 = H2p; unsigned* a19 = H3p;
        float* a20 = H3f;
        void* args[] = {&a0,&a1,&a2,&a3,&a4,&a5,&a6,&a7,&a8,&a9,&a10,&a11,
                        &a12,&a13,&a14,&a15,&a16,&a17,&a18,&a19,&a20};
        hipLaunchCooperativeKernel((void*)fused_scan, dim3(NWG_TOT), dim3(1024),
                                   args, 0, stream);
    }

    // Attention: dot, then fused softmax+context (one fewer launch than R19)
    attn_dot<<<dim3(256), dim3(256), 0, stream>>>(H3f, attnb);
    context_softmax_kernel<<<dim3(256), dim3(256), 0, stream>>>(H3f, attnb, out);
}